// Round 3
// baseline (23448.082 us; speedup 1.0000x reference)
//
#include <hip/hip_runtime.h>
#include <hip/hip_bf16.h>

typedef __attribute__((ext_vector_type(8))) short short8;
typedef __attribute__((ext_vector_type(4))) float floatx4;
typedef unsigned short u16;

// B=128, T=256, D=6, H=512, 4H=2048, NC=4, PS=12

__device__ __forceinline__ u16 f2b(float f){
  union { float fl; unsigned u; } v; v.fl = f;
  unsigned r = v.u + 0x7fffu + ((v.u >> 16) & 1u);   // RNE bf16
  return (u16)(r >> 16);
}

// coherent (agent-scope, L2-bypassing) 16B A-fragment load as 4 dword atomics
__device__ __forceinline__ short8 ld_coh8(const u16* p){
  const unsigned* q = (const unsigned*)p;
  union { unsigned u[4]; short8 s; } v;
  v.u[0] = __hip_atomic_load(q+0, __ATOMIC_RELAXED, __HIP_MEMORY_SCOPE_AGENT);
  v.u[1] = __hip_atomic_load(q+1, __ATOMIC_RELAXED, __HIP_MEMORY_SCOPE_AGENT);
  v.u[2] = __hip_atomic_load(q+2, __ATOMIC_RELAXED, __HIP_MEMORY_SCOPE_AGENT);
  v.u[3] = __hip_atomic_load(q+3, __ATOMIC_RELAXED, __HIP_MEMORY_SCOPE_AGENT);
  return v.s;
}

// ---------------- prep kernels ----------------

__global__ void reorder_w_k(const float* __restrict__ W, u16* __restrict__ out){
  int idx = blockIdx.x*256 + threadIdx.x;       // 2048*512
  int r = idx >> 9, k = idx & 511;
  int rp = ((r & 511) << 2) | (r >> 9);
  out[rp*512 + k] = f2b(W[idx]);
}

__global__ void prep_wx0_k(const float* __restrict__ W, u16* __restrict__ out){
  int idx = blockIdx.x*256 + threadIdx.x;       // 2048*32
  int r = idx >> 5, k = idx & 31;
  int rp = ((r & 511) << 2) | (r >> 9);
  out[rp*32 + k] = (k < 6) ? f2b(W[r*6 + k]) : (u16)0;
}

__global__ void prep_bias_k(const float* __restrict__ bih, const float* __restrict__ bhh,
                            float* __restrict__ out){
  int r = blockIdx.x*256 + threadIdx.x;         // 2048
  int rp = ((r & 511) << 2) | (r >> 9);
  out[rp] = bih[r] + bhh[r];
}

__global__ void prep_x_k(const float* __restrict__ x, u16* __restrict__ out){
  int idx = blockIdx.x*256 + threadIdx.x;       // 256*128*32
  int t = idx >> 12; int rem = idx & 4095; int b = rem >> 5; int k = rem & 31;
  out[idx] = (k < 6) ? f2b(x[(b*256 + t)*6 + k]) : (u16)0;
}

// ---------------- persistent LSTM kernel ----------------

struct PK {
  const u16 *Xb, *Wx0, *W0hh, *W1ih, *W1hh, *Wd0ih, *Wd0hh, *Wd1ih, *Wd1hh;
  const float *Bs;              // 4x2048 gate-interleaved biases: enc0,enc1,dec0,dec1
  u16 *h0b, *h1b;               // bf16 ping-pong h buffers [2][128][512]
  unsigned *flags;              // [0..7]=layer0 per-mt, [8..15]=layer1 per-mt (monotone)
  const float *fcW, *fcb, *clsW, *clsb, *regW, *regb;
  float *out;
};

// One LSTM step tile: gates = bias + A1@W1' + A2@W2', then fused cell update.
// C1/C2: operand needs coherent (agent-scope) loads (true for h buffers).
// h output written as packed u32 agent-scope relaxed atomic stores (bypass L2).
template<bool C1, bool C2>
__device__ __forceinline__ float lstm_step(
    const u16* __restrict__ A1, int K1, const u16* __restrict__ W1,
    const u16* __restrict__ A2, const u16* __restrict__ W2,
    const float* __restrict__ bias, u16* __restrict__ hb, float& creg,
    int m, int nb, int kq, int wave, int lrow, int bl, int jl, int mt, int nt,
    int tid, float (*g)[65], u16 (*hbuf)[18]){
  floatx4 acc = {0.f, 0.f, 0.f, 0.f};
  {
    const u16* Ap = A1 + m*K1 + kq*8;
    const u16* Wp = W1 + nb*K1 + kq*8;
    #pragma unroll 4
    for (int kc = 0; kc < K1; kc += 32){
      short8 a = C1 ? ld_coh8(Ap + kc) : *(const short8*)(Ap + kc);
      short8 b = *(const short8*)(Wp + kc);
      acc = __builtin_amdgcn_mfma_f32_16x16x32_bf16(a, b, acc, 0, 0, 0);
    }
  }
  {
    const u16* Ap = A2 + m*512 + kq*8;
    const u16* Wp = W2 + nb*512 + kq*8;
    #pragma unroll 4
    for (int kc = 0; kc < 512; kc += 32){
      short8 a = C2 ? ld_coh8(Ap + kc) : *(const short8*)(Ap + kc);
      short8 b = *(const short8*)(Wp + kc);
      acc = __builtin_amdgcn_mfma_f32_16x16x32_bf16(a, b, acc, 0, 0, 0);
    }
  }
  // C/D layout: row = kq*4 + r, col = lane&15
  const float bn = bias[nb];
  const int col = wave*16 + lrow;
  #pragma unroll
  for (int r = 0; r < 4; ++r) g[kq*4 + r][col] = acc[r] + bn;
  __syncthreads();
  float gi = g[bl][jl*4+0], gf = g[bl][jl*4+1];
  float gg = g[bl][jl*4+2], go = g[bl][jl*4+3];
  float iv = 1.f/(1.f + expf(-gi));
  float fv = 1.f/(1.f + expf(-gf));
  float ov = 1.f/(1.f + expf(-go));
  float gv = tanhf(gg);
  float cn = fv*creg + iv*gv;
  float hn = ov * tanhf(cn);
  creg = cn;
  hbuf[bl][jl] = f2b(hn);
  __syncthreads();
  if (tid < 128){
    int b = tid >> 3, jw = tid & 7;
    unsigned val = (unsigned)hbuf[b][jw*2] | ((unsigned)hbuf[b][jw*2+1] << 16);
    unsigned* dst = (unsigned*)(hb + (mt*16 + b)*512 + nt*16 + jw*2);
    __hip_atomic_store(dst, val, __ATOMIC_RELAXED, __HIP_MEMORY_SCOPE_AGENT);
  }
  return hn;
}

// wg mapping: xcd = w&7, q = w>>3; layer = q>>5; mt = q&7; nt = xcd*4 + ((q&31)>>3)
// Each XCD owns a fixed 256-column slice of all weight matrices -> L2-resident.
// Flags: monotone counters, 32 producers per (layer, mt) per slot.
// NO fences anywhere: all cross-wg data moves via agent-scope (sc0 sc1) atomics
// that bypass the non-coherent per-XCD L2. Producer order: __syncthreads drains
// vmcnt before tid0 bumps the flag. Consumer order: data loads issue after the
// data-dependent branch on the polled flag.

__global__ __launch_bounds__(256, 2) void persist_k(PK p){
  const int tid  = threadIdx.x;
  const int w    = blockIdx.x;
  const int xcd  = w & 7;
  const int q    = w >> 3;
  const int layer= q >> 5;
  const int mt   = q & 7;
  const int nt   = xcd*4 + ((q & 31) >> 3);
  const int wave = tid >> 6, lane = tid & 63;
  const int lrow = lane & 15, kq = lane >> 4;
  const int m    = mt*16 + lrow;
  const int nb   = nt*64 + wave*16 + lrow;
  const int bl   = tid & 15, jl = tid >> 4;
  const int HB   = 128*512;
  __shared__ float g[16][65];
  __shared__ u16 hbuf[16][18];
  unsigned* f0 = p.flags + mt;
  unsigned* f1 = p.flags + 8 + mt;
  float creg = 0.f;   // register-resident cell state for the whole run

  auto waits = [&](unsigned* fa, unsigned va, unsigned* fb, unsigned vb){
    if (tid == 0){
      while (__hip_atomic_load(fa, __ATOMIC_RELAXED, __HIP_MEMORY_SCOPE_AGENT) < va)
        __builtin_amdgcn_s_sleep(1);
      while (__hip_atomic_load(fb, __ATOMIC_RELAXED, __HIP_MEMORY_SCOPE_AGENT) < vb)
        __builtin_amdgcn_s_sleep(1);
    }
    __syncthreads();
  };
  auto release = [&](unsigned* f){
    __syncthreads();     // compiler emits s_waitcnt vmcnt(0) before s_barrier
    if (tid == 0)
      __hip_atomic_fetch_add(f, 1u, __ATOMIC_RELAXED, __HIP_MEMORY_SCOPE_AGENT);
  };

  if (layer == 0){
    // encoder layer0: slot t in 0..255
    for (int t = 0; t < 256; ++t){
      waits(f0, 32u*t, f1, (t >= 1) ? 32u*(t-1) : 0u);
      lstm_step<false,true>(p.Xb + t*4096, 32, p.Wx0,
           p.h0b + ((t+1)&1)*HB, p.W0hh, p.Bs, p.h0b + (t&1)*HB, creg,
           m, nb, kq, wave, lrow, bl, jl, mt, nt, tid, g, hbuf);
      release(f0);
    }
    // decoder layer0: slots s in 0..11
    for (int s = 0; s < 12; ++s){
      int ps = (s&1) ^ 1;
      waits(f0, 32u*(256+s), f1, 32u*(256+s));
      lstm_step<true,true>(p.h1b + ps*HB, 512, p.Wd0ih,
           p.h0b + ps*HB, p.Wd0hh, p.Bs + 4096, p.h0b + (1-ps)*HB, creg,
           m, nb, kq, wave, lrow, bl, jl, mt, nt, tid, g, hbuf);
      release(f0);
    }
  } else {
    // encoder layer1: u in 0..255 (runs at slot u+1)
    for (int u = 0; u < 256; ++u){
      waits(f0, 32u*(u+1), f1, 32u*u);
      float hn = lstm_step<true,true>(p.h0b + (u&1)*HB, 512, p.W1ih,
           p.h1b + ((u+1)&1)*HB, p.W1hh, p.Bs + 2048, p.h1b + (u&1)*HB, creg,
           m, nb, kq, wave, lrow, bl, jl, mt, nt, tid, g, hbuf);
      if (u == 255){
        // heads from fp32 last hidden
        __syncthreads();
        float* hsf = (float*)g;
        hsf[bl*16 + jl] = hn;
        __syncthreads();
        if (tid < 80){
          int b = tid / 5, d2 = tid % 5;
          float v = 0.f;
          if (d2 < 4){
            for (int j = 0; j < 16; ++j) v += hsf[b*16 + j] * p.clsW[d2*512 + nt*16 + j];
            if (nt == 0) v += p.clsb[d2];
            atomicAdd(&p.out[9216 + (mt*16 + b)*4 + d2], v);
          } else {
            for (int j = 0; j < 16; ++j) v += hsf[b*16 + j] * p.regW[nt*16 + j];
            if (nt == 0) v += p.regb[0];
            atomicAdd(&p.out[9728 + (mt*16 + b)], v);
          }
        }
        __syncthreads();
      }
      release(f1);
    }
    // decoder layer1 + forecast: s in 0..11
    for (int s = 0; s < 12; ++s){
      int ps = (s&1) ^ 1;
      waits(f0, 32u*(257+s), f1, 32u*(256+s));
      float hn = lstm_step<true,true>(p.h0b + (1-ps)*HB, 512, p.Wd1ih,
           p.h1b + ps*HB, p.Wd1hh, p.Bs + 6144, p.h1b + (1-ps)*HB, creg,
           m, nb, kq, wave, lrow, bl, jl, mt, nt, tid, g, hbuf);
      __syncthreads();
      float* hsf = (float*)g;
      hsf[bl*16 + jl] = hn;
      __syncthreads();
      if (tid < 96){
        int b = tid / 6, d2 = tid % 6;
        float v = 0.f;
        for (int j = 0; j < 16; ++j) v += hsf[b*16 + j] * p.fcW[d2*512 + nt*16 + j];
        if (nt == 0) v += p.fcb[d2];
        atomicAdd(&p.out[(mt*16 + b)*72 + s*6 + d2], v);
      }
      __syncthreads();
      release(f1);
    }
  }
}

// ---------------- launcher ----------------

extern "C" void kernel_launch(void* const* d_in, const int* in_sizes, int n_in,
                              void* d_out, int out_size, void* d_ws, size_t ws_size,
                              hipStream_t stream){
  const float* x        = (const float*)d_in[0];
  const float* eWih0    = (const float*)d_in[1];
  const float* eWhh0    = (const float*)d_in[2];
  const float* ebih0    = (const float*)d_in[3];
  const float* ebhh0    = (const float*)d_in[4];
  const float* eWih1    = (const float*)d_in[5];
  const float* eWhh1    = (const float*)d_in[6];
  const float* ebih1    = (const float*)d_in[7];
  const float* ebhh1    = (const float*)d_in[8];
  const float* dWih0    = (const float*)d_in[9];
  const float* dWhh0    = (const float*)d_in[10];
  const float* dbih0    = (const float*)d_in[11];
  const float* dbhh0    = (const float*)d_in[12];
  const float* dWih1    = (const float*)d_in[13];
  const float* dWhh1    = (const float*)d_in[14];
  const float* dbih1    = (const float*)d_in[15];
  const float* dbhh1    = (const float*)d_in[16];
  const float* fcW      = (const float*)d_in[17];
  const float* fcb      = (const float*)d_in[18];
  const float* clsW     = (const float*)d_in[19];
  const float* clsb     = (const float*)d_in[20];
  const float* regW     = (const float*)d_in[21];
  const float* regb     = (const float*)d_in[22];
  float* out = (float*)d_out;

  uintptr_t base = (uintptr_t)d_ws;
  auto carve = [&](size_t n)->void*{
    void* p = (void*)base; base += (n + 255) & ~(size_t)255; return p;
  };
  u16* Wx0b  = (u16*)carve(2048*32*2);
  u16* We0hh = (u16*)carve(2048*512*2);
  u16* We1ih = (u16*)carve(2048*512*2);
  u16* We1hh = (u16*)carve(2048*512*2);
  u16* Wd0ih = (u16*)carve(2048*512*2);
  u16* Wd0hh = (u16*)carve(2048*512*2);
  u16* Wd1ih = (u16*)carve(2048*512*2);
  u16* Wd1hh = (u16*)carve(2048*512*2);
  float* Bs  = (float*)carve(4*2048*4);          // enc0, enc1, dec0, dec1
  u16* Xb    = (u16*)carve(256*128*32*2);
  u16* h0b   = (u16*)carve(2*128*512*2);         // ping-pong bf16 h
  u16* h1b   = (u16*)carve(2*128*512*2);
  unsigned* flags = (unsigned*)carve(64*4);

  // zero h-buffers + flags (contiguous, 256-aligned carves)
  hipMemsetAsync(h0b, 0, 2*128*512*2 + 2*128*512*2 + 256, stream);
  // out is accumulated via atomicAdd
  hipMemsetAsync(out, 0, (size_t)out_size*4, stream);

  reorder_w_k<<<4096,256,0,stream>>>(eWhh0, We0hh);
  reorder_w_k<<<4096,256,0,stream>>>(eWih1, We1ih);
  reorder_w_k<<<4096,256,0,stream>>>(eWhh1, We1hh);
  reorder_w_k<<<4096,256,0,stream>>>(dWih0, Wd0ih);
  reorder_w_k<<<4096,256,0,stream>>>(dWhh0, Wd0hh);
  reorder_w_k<<<4096,256,0,stream>>>(dWih1, Wd1ih);
  reorder_w_k<<<4096,256,0,stream>>>(dWhh1, Wd1hh);
  prep_wx0_k<<<256,256,0,stream>>>(eWih0, Wx0b);
  prep_bias_k<<<8,256,0,stream>>>(ebih0, ebhh0, Bs);
  prep_bias_k<<<8,256,0,stream>>>(ebih1, ebhh1, Bs + 2048);
  prep_bias_k<<<8,256,0,stream>>>(dbih0, dbhh0, Bs + 4096);
  prep_bias_k<<<8,256,0,stream>>>(dbih1, dbhh1, Bs + 6144);
  prep_x_k<<<4096,256,0,stream>>>(x, Xb);

  PK p;
  p.Xb = Xb; p.Wx0 = Wx0b; p.W0hh = We0hh; p.W1ih = We1ih; p.W1hh = We1hh;
  p.Wd0ih = Wd0ih; p.Wd0hh = Wd0hh; p.Wd1ih = Wd1ih; p.Wd1hh = Wd1hh;
  p.Bs = Bs; p.h0b = h0b; p.h1b = h1b; p.flags = flags;
  p.fcW = fcW; p.fcb = fcb; p.clsW = clsW; p.clsb = clsb;
  p.regW = regW; p.regb = regb; p.out = out;

  void* args[] = { &p };
  hipLaunchCooperativeKernel((const void*)persist_k, dim3(512), dim3(256),
                             args, 0, stream);
  (void)in_sizes; (void)n_in; (void)ws_size;
}

// Round 5
// 3957.073 us; speedup vs baseline: 5.9256x; 5.9256x over previous
//
#include <hip/hip_runtime.h>
#include <hip/hip_bf16.h>

typedef __attribute__((ext_vector_type(8))) short short8;
typedef __attribute__((ext_vector_type(4))) float floatx4;
typedef unsigned short u16;
typedef unsigned long long u64;

#define SCOPE_AGENT __HIP_MEMORY_SCOPE_AGENT

// B=128, T=256, D=6, H=512, 4H=2048, NC=4, PS=12

__device__ __forceinline__ u16 f2b(float f){
  union { float fl; unsigned u; } v; v.fl = f;
  unsigned r = v.u + 0x7fffu + ((v.u >> 16) & 1u);   // RNE bf16
  return (u16)(r >> 16);
}
__device__ __forceinline__ float b2f(u16 b){
  union { unsigned u; float f; } v; v.u = ((unsigned)b) << 16; return v.f;
}

// coherent (agent-scope, L2-bypassing) loads/stores for cross-XCD h exchange
__device__ __forceinline__ short8 ldc8(const u16* p){
  union { u64 q[2]; short8 s; } v;
  v.q[0] = __hip_atomic_load((const u64*)p,       __ATOMIC_RELAXED, SCOPE_AGENT);
  v.q[1] = __hip_atomic_load(((const u64*)p) + 1, __ATOMIC_RELAXED, SCOPE_AGENT);
  return v.s;
}
__device__ __forceinline__ u64 ldc64(const u64* p){
  return __hip_atomic_load(p, __ATOMIC_RELAXED, SCOPE_AGENT);
}
__device__ __forceinline__ void stc64(u64* p, u64 v){
  __hip_atomic_store(p, v, __ATOMIC_RELAXED, SCOPE_AGENT);
}

// ---------------- prep kernels ----------------

// (2048,512) fp32 -> bf16, rows reordered r=gate*512+j -> r'=j*4+gate
__global__ void reorder_w_k(const float* __restrict__ W, u16* __restrict__ out){
  int idx = blockIdx.x*256 + threadIdx.x;       // 2048*512
  int r = idx >> 9, k = idx & 511;
  int rp = ((r & 511) << 2) | (r >> 9);
  out[rp*512 + k] = f2b(W[idx]);
}

// enc_Wih0 (2048,6) -> (2048,32) bf16 zero-padded, rows reordered
__global__ void prep_wx0_k(const float* __restrict__ W, u16* __restrict__ out){
  int idx = blockIdx.x*256 + threadIdx.x;       // 2048*32
  int r = idx >> 5, k = idx & 31;
  int rp = ((r & 511) << 2) | (r >> 9);
  out[rp*32 + k] = (k < 6) ? f2b(W[r*6 + k]) : (u16)0;
}

__global__ void prep_bias_k(const float* __restrict__ bih, const float* __restrict__ bhh,
                            float* __restrict__ out){
  int r = blockIdx.x*256 + threadIdx.x;         // 2048
  int rp = ((r & 511) << 2) | (r >> 9);
  out[rp] = bih[r] + bhh[r];
}

// x (B,T,6) fp32 -> Xb (T,B,32) bf16 zero-padded
__global__ void prep_x_k(const float* __restrict__ x, u16* __restrict__ out){
  int idx = blockIdx.x*256 + threadIdx.x;       // 256*128*32
  int t = idx >> 12; int rem = idx & 4095; int b = rem >> 5; int k = rem & 31;
  out[idx] = (k < 6) ? f2b(x[(b*256 + t)*6 + k]) : (u16)0;
}

// ---------------- persistent LSTM kernel ----------------

struct PK {
  const u16 *Xb, *Wx0, *W0hh, *W1ih, *W1hh, *Wd0ih, *Wd0hh, *Wd1ih, *Wd1hh;
  const float *Bs;              // 4x2048 gate-interleaved biases: enc0,enc1,dec0,dec1
  u16 *h0b, *h1b;               // bf16 ping-pong h buffers [2][128][512]
  unsigned *flags;              // [0..63]=f0 (l0, mh*32+nt), [64..127]=f1, [128..129]=fh
  const float *fcW, *fcb, *clsW, *clsb, *regW, *regb;
  float *out;
};

// One LSTM step tile for wg (nt, mh): 64 batches (mh half) x 64 gates (nt slice),
// gates = bias + A1@W1' + A2@W2'. Weights in LDS (stride st1 / 520, +8 pad).
// A operands: full rows of h (or Xb), prefetched to registers; h via b64 agent
// atomics (cross-XCD coherent), Xb via plain loads.
// wave wv owns m-tile wv (16 batches) x 4 n-tiles.
template<int NK1, bool COH1>
__device__ __forceinline__ void lstm_step(
    const u16* __restrict__ A1, int a1rowlen, const u16* __restrict__ ldsW1, int st1,
    const u16* __restrict__ A2, const u16* __restrict__ ldsW2,
    const float* __restrict__ biasp,    // &Bs[layer_off + nt*64]
    u16* __restrict__ hdst,             // h slot base
    float* creg,                        // [4] cell state (b=tid&63, j=jg*4+jj)
    float (*g)[68], u16 (*hbuf)[16],
    int mh, int nt, int wv, int lane, int tid)
{
  const int lrow = lane & 15, kq = lane >> 4;
  const int arow = mh*64 + wv*16 + lrow;
  short8 a1[NK1], a2[16];
  {
    const u16* p1 = A1 + arow*a1rowlen + kq*8;
    #pragma unroll
    for (int k = 0; k < NK1; ++k)
      a1[k] = COH1 ? ldc8(p1 + k*32) : *(const short8*)(p1 + k*32);
    const u16* p2 = A2 + arow*512 + kq*8;
    #pragma unroll
    for (int k = 0; k < 16; ++k) a2[k] = ldc8(p2 + k*32);
  }
  floatx4 acc[4];
  #pragma unroll
  for (int nn = 0; nn < 4; ++nn) acc[nn] = (floatx4){0.f,0.f,0.f,0.f};
  #pragma unroll
  for (int nn = 0; nn < 4; ++nn){
    const u16* wb = ldsW1 + (nn*16 + lrow)*st1 + kq*8;
    #pragma unroll
    for (int k = 0; k < NK1; ++k)
      acc[nn] = __builtin_amdgcn_mfma_f32_16x16x32_bf16(a1[k], *(const short8*)(wb + k*32), acc[nn], 0,0,0);
  }
  #pragma unroll
  for (int nn = 0; nn < 4; ++nn){
    const u16* wb = ldsW2 + (nn*16 + lrow)*520 + kq*8;
    #pragma unroll
    for (int k = 0; k < 16; ++k)
      acc[nn] = __builtin_amdgcn_mfma_f32_16x16x32_bf16(a2[k], *(const short8*)(wb + k*32), acc[nn], 0,0,0);
  }
  // C/D layout: row(m) = kq*4 + r, col(n) = lane&15
  #pragma unroll
  for (int nn = 0; nn < 4; ++nn){
    float bn = biasp[nn*16 + lrow];
    #pragma unroll
    for (int r = 0; r < 4; ++r)
      g[wv*16 + kq*4 + r][nn*16 + lrow] = acc[nn][r] + bn;
  }
  __syncthreads();
  // fused cell update: thread -> (b = tid&63, j = jg*4+jj)
  const int b = tid & 63, jg = tid >> 6;
  union { u16 h[4]; u64 q; } pk;
  #pragma unroll
  for (int jj = 0; jj < 4; ++jj){
    float gi = g[b][jg*16 + jj*4 + 0];
    float gf = g[b][jg*16 + jj*4 + 1];
    float gg = g[b][jg*16 + jj*4 + 2];
    float go = g[b][jg*16 + jj*4 + 3];
    float iv = 1.f/(1.f + expf(-gi));
    float fv = 1.f/(1.f + expf(-gf));
    float ov = 1.f/(1.f + expf(-go));
    float cn = fv*creg[jj] + iv*tanhf(gg);
    creg[jj] = cn;
    pk.h[jj] = f2b(ov * tanhf(cn));
  }
  *(u64*)&hbuf[b][jg*4] = pk.q;
  __syncthreads();
  {
    int bb = tid >> 2, qq = tid & 3;
    u64 v = *(const u64*)&hbuf[bb][qq*4];
    stc64((u64*)(hdst + (mh*64 + bb)*512 + nt*16 + qq*4), v);
  }
}

// Flag protocol (all single-producer, monotone, relaxed agent atomics):
//  f0[mh*32+nt]: l0 wg; enc step t -> t+1 (max 256); dec step s -> 257+s.
//  f1[...]: l1 wg; enc u -> u+1; dec s -> 257+s.
//  fh[mh]: head wg; after enc heads -> 1; after forecast s -> s+2.
// Waits (derived + hazard-checked, incl. ping-pong WAR):
//  enc l0 t: f0>=t, f1>=t-1         enc l1 u: f0>=u+1, f1>=u
//  dec l0 s: f0>=256+s, f1>=256+s   dec l1 s: f0>=257+s, f1>=256+s, fh>=s
//  heads: f1>=256                   forecast s: f1>=257+s

__global__ __launch_bounds__(256, 1) void persist_k(PK p){
  const int w = blockIdx.x, tid = threadIdx.x;
  const int wv = tid >> 6, lane = tid & 63;
  __shared__ float g[64][68];
  __shared__ u16 hbuf[64][16];
  extern __shared__ u16 dynW[];
  const int HB = 65536;
  unsigned* F = p.flags;

  auto wait3 = [&](int n0, int n1, int nh){
    if (tid < 64){
      while (true){
        int v0 = (int)__hip_atomic_load(F + tid,      __ATOMIC_RELAXED, SCOPE_AGENT);
        int v1 = (int)__hip_atomic_load(F + 64 + tid, __ATOMIC_RELAXED, SCOPE_AGENT);
        bool pass = (v0 >= n0) && (v1 >= n1);
        if (nh >= 0 && tid < 2)
          pass = pass && ((int)__hip_atomic_load(F + 128 + tid, __ATOMIC_RELAXED, SCOPE_AGENT) >= nh);
        if (__all(pass)) break;
        bool far = __any((n0 - v0 > 2) || (n1 - v1 > 2));
        if (far) __builtin_amdgcn_s_sleep(32);
        else     __builtin_amdgcn_s_sleep(1);
      }
    }
    __syncthreads();
  };
  auto setflag = [&](int idx, unsigned val){
    __syncthreads();   // each wave drains vmcnt (h stores) before s_barrier
    if (tid == 0) __hip_atomic_store(F + idx, val, __ATOMIC_RELAXED, SCOPE_AGENT);
  };

  if (w < 128){
    const int role = w >> 6;            // 0 = layer0 chain, 1 = layer1 chain
    const int nt = w & 31, mh = (w >> 5) & 1;
    const int fidx = role*64 + mh*32 + nt;
    u16* WA = dynW;
    u16* WB = dynW + 64*520;
    float creg[4] = {0.f, 0.f, 0.f, 0.f};

    if (role == 0){
      { // preload: Wx0 slice (stride 40) + W0hh slice (stride 520)
        const unsigned* sA = (const unsigned*)(p.Wx0 + nt*64*32);
        unsigned* dA = (unsigned*)WA;
        for (int i = tid; i < 64*16; i += 256){ int r = i>>4, c = i&15; dA[r*20+c] = sA[r*16+c]; }
        const unsigned* sB = (const unsigned*)(p.W0hh + (size_t)nt*64*512);
        unsigned* dB = (unsigned*)WB;
        for (int i = tid; i < 64*256; i += 256){ int r = i>>8, c = i&255; dB[r*260+c] = sB[r*256+c]; }
      }
      const float* biasp = p.Bs + nt*64;
      for (int t = 0; t < 256; ++t){
        wait3(t, t-1, -1);
        lstm_step<1,false>(p.Xb + t*4096, 32, WA, 40,
                           p.h0b + ((t+1)&1)*HB, WB,
                           biasp, p.h0b + (t&1)*HB, creg, g, hbuf, mh, nt, wv, lane, tid);
        setflag(fidx, t+1);
      }
      { // reload decoder l0 weights (cell state stays in regs)
        const unsigned* sA = (const unsigned*)(p.Wd0ih + (size_t)nt*64*512);
        const unsigned* sB = (const unsigned*)(p.Wd0hh + (size_t)nt*64*512);
        unsigned* dA = (unsigned*)WA; unsigned* dB = (unsigned*)WB;
        for (int i = tid; i < 64*256; i += 256){
          int r = i>>8, c = i&255;
          dA[r*260+c] = sA[r*256+c]; dB[r*260+c] = sB[r*256+c];
        }
      }
      biasp = p.Bs + 4096 + nt*64;
      for (int s = 0; s < 12; ++s){
        int ps = (s&1)^1;
        wait3(256+s, 256+s, -1);
        lstm_step<16,true>(p.h1b + ps*HB, 512, WA, 520,
                           p.h0b + ps*HB, WB,
                           biasp, p.h0b + (1-ps)*HB, creg, g, hbuf, mh, nt, wv, lane, tid);
        setflag(fidx, 257+s);
      }
    } else {
      { // preload: W1ih + W1hh slices
        const unsigned* sA = (const unsigned*)(p.W1ih + (size_t)nt*64*512);
        const unsigned* sB = (const unsigned*)(p.W1hh + (size_t)nt*64*512);
        unsigned* dA = (unsigned*)WA; unsigned* dB = (unsigned*)WB;
        for (int i = tid; i < 64*256; i += 256){
          int r = i>>8, c = i&255;
          dA[r*260+c] = sA[r*256+c]; dB[r*260+c] = sB[r*256+c];
        }
      }
      const float* biasp = p.Bs + 2048 + nt*64;
      for (int u = 0; u < 256; ++u){
        wait3(u+1, u, -1);
        lstm_step<16,true>(p.h0b + (u&1)*HB, 512, WA, 520,
                           p.h1b + ((u+1)&1)*HB, WB,
                           biasp, p.h1b + (u&1)*HB, creg, g, hbuf, mh, nt, wv, lane, tid);
        setflag(fidx, u+1);
      }
      { // reload decoder l1 weights
        const unsigned* sA = (const unsigned*)(p.Wd1ih + (size_t)nt*64*512);
        const unsigned* sB = (const unsigned*)(p.Wd1hh + (size_t)nt*64*512);
        unsigned* dA = (unsigned*)WA; unsigned* dB = (unsigned*)WB;
        for (int i = tid; i < 64*256; i += 256){
          int r = i>>8, c = i&255;
          dA[r*260+c] = sA[r*256+c]; dB[r*260+c] = sB[r*256+c];
        }
      }
      biasp = p.Bs + 6144 + nt*64;
      for (int s = 0; s < 12; ++s){
        int ps = (s&1)^1;
        wait3(257+s, 256+s, s);
        lstm_step<16,true>(p.h0b + (1-ps)*HB, 512, WA, 520,
                           p.h1b + ps*HB, WB,
                           biasp, p.h1b + (1-ps)*HB, creg, g, hbuf, mh, nt, wv, lane, tid);
        setflag(fidx, 257+s);
      }
    }
  } else if (w < 130){
    // head wg (one per mh half): enc heads at t=255, then forecast per dec step
    const int mh = w & 1;
    const int b = tid & 63, part = tid >> 6;
    const int gb = mh*64 + b;
    { // cls + reg from h1[255] (slot 1)
      wait3(0, 256, -1);
      const u64* hp = (const u64*)(p.h1b + HB + gb*512 + part*128);
      float a[5] = {0.f,0.f,0.f,0.f,0.f};
      for (int c = 0; c < 32; ++c){
        u64 v = ldc64(hp + c);
        #pragma unroll
        for (int e = 0; e < 4; ++e){
          float hv = b2f((u16)(v >> (16*e)));
          int k = part*128 + c*4 + e;
          a[0] += hv * p.clsW[k];
          a[1] += hv * p.clsW[512 + k];
          a[2] += hv * p.clsW[1024 + k];
          a[3] += hv * p.clsW[1536 + k];
          a[4] += hv * p.regW[k];
        }
      }
      #pragma unroll
      for (int d = 0; d < 5; ++d) g[b][part*8 + d] = a[d];
      __syncthreads();
      if (tid < 64){
        #pragma unroll
        for (int d = 0; d < 5; ++d){
          float v = g[tid][d] + g[tid][8+d] + g[tid][16+d] + g[tid][24+d];
          if (d < 4) p.out[9216 + (mh*64 + tid)*4 + d] = v + p.clsb[d];
          else       p.out[9728 + mh*64 + tid]         = v + p.regb[0];
        }
      }
      __syncthreads();
      if (tid == 0) __hip_atomic_store(F + 128 + mh, 1u, __ATOMIC_RELAXED, SCOPE_AGENT);
    }
    for (int s = 0; s < 12; ++s){
      wait3(0, 257+s, -1);
      const u64* hp = (const u64*)(p.h1b + (s&1)*HB + gb*512 + part*128);
      float a[6] = {0.f,0.f,0.f,0.f,0.f,0.f};
      for (int c = 0; c < 32; ++c){
        u64 v = ldc64(hp + c);
        #pragma unroll
        for (int e = 0; e < 4; ++e){
          float hv = b2f((u16)(v >> (16*e)));
          int k = part*128 + c*4 + e;
          #pragma unroll
          for (int d = 0; d < 6; ++d) a[d] += hv * p.fcW[d*512 + k];
        }
      }
      #pragma unroll
      for (int d = 0; d < 6; ++d) g[b][part*8 + d] = a[d];
      __syncthreads();
      if (tid < 64){
        #pragma unroll
        for (int d = 0; d < 6; ++d){
          float v = g[tid][d] + g[tid][8+d] + g[tid][16+d] + g[tid][24+d];
          p.out[(mh*64 + tid)*72 + s*6 + d] = v + p.fcb[d];
        }
      }
      __syncthreads();
      if (tid == 0) __hip_atomic_store(F + 128 + mh, (unsigned)(s+2), __ATOMIC_RELAXED, SCOPE_AGENT);
    }
  }
}

// ---------------- launcher ----------------

extern "C" void kernel_launch(void* const* d_in, const int* in_sizes, int n_in,
                              void* d_out, int out_size, void* d_ws, size_t ws_size,
                              hipStream_t stream){
  const float* x     = (const float*)d_in[0];
  const float* eWih0 = (const float*)d_in[1];
  const float* eWhh0 = (const float*)d_in[2];
  const float* ebih0 = (const float*)d_in[3];
  const float* ebhh0 = (const float*)d_in[4];
  const float* eWih1 = (const float*)d_in[5];
  const float* eWhh1 = (const float*)d_in[6];
  const float* ebih1 = (const float*)d_in[7];
  const float* ebhh1 = (const float*)d_in[8];
  const float* dWih0 = (const float*)d_in[9];
  const float* dWhh0 = (const float*)d_in[10];
  const float* dbih0 = (const float*)d_in[11];
  const float* dbhh0 = (const float*)d_in[12];
  const float* dWih1 = (const float*)d_in[13];
  const float* dWhh1 = (const float*)d_in[14];
  const float* dbih1 = (const float*)d_in[15];
  const float* dbhh1 = (const float*)d_in[16];
  const float* fcW   = (const float*)d_in[17];
  const float* fcb   = (const float*)d_in[18];
  const float* clsW  = (const float*)d_in[19];
  const float* clsb  = (const float*)d_in[20];
  const float* regW  = (const float*)d_in[21];
  const float* regb  = (const float*)d_in[22];
  float* out = (float*)d_out;

  uintptr_t base = (uintptr_t)d_ws;
  auto carve = [&](size_t n)->void*{
    void* p = (void*)base; base += (n + 255) & ~(size_t)255; return p;
  };
  u16* Wx0b  = (u16*)carve(2048*32*2);
  u16* We0hh = (u16*)carve(2048*512*2);
  u16* We1ih = (u16*)carve(2048*512*2);
  u16* We1hh = (u16*)carve(2048*512*2);
  u16* Wd0ih = (u16*)carve(2048*512*2);
  u16* Wd0hh = (u16*)carve(2048*512*2);
  u16* Wd1ih = (u16*)carve(2048*512*2);
  u16* Wd1hh = (u16*)carve(2048*512*2);
  float* Bs  = (float*)carve(4*2048*4);
  u16* Xb    = (u16*)carve(256*128*32*2);
  u16* h0b   = (u16*)carve(2*128*512*2);      // ping-pong bf16 h, layer0
  u16* h1b   = (u16*)carve(2*128*512*2);      // layer1
  unsigned* flags = (unsigned*)carve(192*4);

  // zero h-buffers + flags (contiguous 256-aligned carves)
  (void)hipMemsetAsync(h0b, 0, 2*128*512*2 + 2*128*512*2 + 768, stream);

  reorder_w_k<<<4096,256,0,stream>>>(eWhh0, We0hh);
  reorder_w_k<<<4096,256,0,stream>>>(eWih1, We1ih);
  reorder_w_k<<<4096,256,0,stream>>>(eWhh1, We1hh);
  reorder_w_k<<<4096,256,0,stream>>>(dWih0, Wd0ih);
  reorder_w_k<<<4096,256,0,stream>>>(dWhh0, Wd0hh);
  reorder_w_k<<<4096,256,0,stream>>>(dWih1, Wd1ih);
  reorder_w_k<<<4096,256,0,stream>>>(dWhh1, Wd1hh);
  prep_wx0_k<<<256,256,0,stream>>>(eWih0, Wx0b);
  prep_bias_k<<<8,256,0,stream>>>(ebih0, ebhh0, Bs);
  prep_bias_k<<<8,256,0,stream>>>(ebih1, ebhh1, Bs + 2048);
  prep_bias_k<<<8,256,0,stream>>>(dbih0, dbhh0, Bs + 4096);
  prep_bias_k<<<8,256,0,stream>>>(dbih1, dbhh1, Bs + 6144);
  prep_x_k<<<4096,256,0,stream>>>(x, Xb);

  PK p;
  p.Xb = Xb; p.Wx0 = Wx0b; p.W0hh = We0hh; p.W1ih = We1ih; p.W1hh = We1hh;
  p.Wd0ih = Wd0ih; p.Wd0hh = Wd0hh; p.Wd1ih = Wd1ih; p.Wd1hh = Wd1hh;
  p.Bs = Bs; p.h0b = h0b; p.h1b = h1b; p.flags = flags;
  p.fcW = fcW; p.fcb = fcb; p.clsW = clsW; p.clsb = clsb;
  p.regW = regW; p.regb = regb; p.out = out;

  const int dynLds = 2*64*520*2;   // 133,120 B (two 64x520 u16 weight slices)
  (void)hipFuncSetAttribute((const void*)persist_k,
                            hipFuncAttributeMaxDynamicSharedMemorySize, dynLds);

  void* args[] = { &p };
  (void)hipLaunchCooperativeKernel((const void*)persist_k, dim3(130), dim3(256),
                                   args, dynLds, stream);
  (void)in_sizes; (void)n_in; (void)out_size; (void)ws_size;
}

// Round 7
// 3576.977 us; speedup vs baseline: 6.5553x; 1.1063x over previous
//
#include <hip/hip_runtime.h>
#include <hip/hip_bf16.h>

typedef __attribute__((ext_vector_type(8))) short short8;
typedef __attribute__((ext_vector_type(4))) float floatx4;
typedef unsigned short u16;
typedef unsigned long long u64;

#define SCOPE_AGENT __HIP_MEMORY_SCOPE_AGENT

// B=128, T=256, D=6, H=512, 4H=2048, NC=4, PS=12

__device__ __forceinline__ u16 f2b(float f){
  union { float fl; unsigned u; } v; v.fl = f;
  unsigned r = v.u + 0x7fffu + ((v.u >> 16) & 1u);   // RNE bf16
  return (u16)(r >> 16);
}
__device__ __forceinline__ float b2f(u16 b){
  union { unsigned u; float f; } v; v.u = ((unsigned)b) << 16; return v.f;
}

// coherent (agent-scope, L2-bypassing) loads/stores for cross-XCD h exchange
__device__ __forceinline__ short8 ldc8(const u16* p){
  union { u64 q[2]; short8 s; } v;
  v.q[0] = __hip_atomic_load((const u64*)p,       __ATOMIC_RELAXED, SCOPE_AGENT);
  v.q[1] = __hip_atomic_load(((const u64*)p) + 1, __ATOMIC_RELAXED, SCOPE_AGENT);
  return v.s;
}
__device__ __forceinline__ u64 ldc64(const u64* p){
  return __hip_atomic_load(p, __ATOMIC_RELAXED, SCOPE_AGENT);
}
__device__ __forceinline__ void stc64(u64* p, u64 v){
  __hip_atomic_store(p, v, __ATOMIC_RELAXED, SCOPE_AGENT);
}

// ---------------- prep kernels ----------------

// (2048,512) fp32 -> bf16, rows reordered r=gate*512+j -> r'=j*4+gate
__global__ void reorder_w_k(const float* __restrict__ W, u16* __restrict__ out){
  int idx = blockIdx.x*256 + threadIdx.x;       // 2048*512
  int r = idx >> 9, k = idx & 511;
  int rp = ((r & 511) << 2) | (r >> 9);
  out[rp*512 + k] = f2b(W[idx]);
}
__global__ void prep_wx0_k(const float* __restrict__ W, u16* __restrict__ out){
  int idx = blockIdx.x*256 + threadIdx.x;       // 2048*32
  int r = idx >> 5, k = idx & 31;
  int rp = ((r & 511) << 2) | (r >> 9);
  out[rp*32 + k] = (k < 6) ? f2b(W[r*6 + k]) : (u16)0;
}
__global__ void prep_bias_k(const float* __restrict__ bih, const float* __restrict__ bhh,
                            float* __restrict__ out){
  int r = blockIdx.x*256 + threadIdx.x;         // 2048
  int rp = ((r & 511) << 2) | (r >> 9);
  out[rp] = bih[r] + bhh[r];
}
__global__ void prep_x_k(const float* __restrict__ x, u16* __restrict__ out){
  int idx = blockIdx.x*256 + threadIdx.x;       // 256*128*32
  int t = idx >> 12; int rem = idx & 4095; int b = rem >> 5; int k = rem & 31;
  out[idx] = (k < 6) ? f2b(x[(b*256 + t)*6 + k]) : (u16)0;
}

// ---------------- persistent LSTM kernel ----------------

struct PK {
  const u16 *Xb, *Wx0, *W0hh, *W1ih, *W1hh, *Wd0ih, *Wd0hh, *Wd1ih, *Wd1hh;
  const float *Bs;              // 4x2048 gate-interleaved biases
  u16 *h0b, *h1b;               // bf16 ping-pong h buffers [2][128][512]
  unsigned *F;                  // [0..63]=l0 (mh*32+nt), [64..127]=l1, [128..129]=heads
  const float *fcW, *fcb, *clsW, *clsb, *regW, *regb;
  float *out;
};

#define HB 65536

// all-wave flag poll (no barrier needed after: condition is monotone)
__device__ __forceinline__ void pollF(const unsigned* F, int mh, int thr0, int thr1, int thrh){
  const int lane = threadIdx.x & 63;
  const unsigned* ap = (lane < 32) ? (F + mh*32 + lane) : (F + 64 + mh*32 + (lane - 32));
  const int thr = (lane < 32) ? thr0 : thr1;
  for(;;){
    int v = (int)__hip_atomic_load(ap, __ATOMIC_RELAXED, SCOPE_AGENT);
    bool ok = (v >= thr);
    if (thrh > 0 && lane == 0)
      ok = ok && ((int)__hip_atomic_load(F + 128 + mh, __ATOMIC_RELAXED, SCOPE_AGENT) >= thrh);
    if (__all(ok)) return;
    if (__any((thr - v) > 2)) __builtin_amdgcn_s_sleep(16);
    else                      __builtin_amdgcn_s_sleep(1);
  }
}

// One LSTM step tile for wg (role, mh, nt): 64 batches x 64 gates.
// Weights in LDS; A rows prefetched to regs (coherent b64 atomics for h).
// Epilogue transpose is INTRA-WAVE (wave wv touches only g rows wv*16..+15),
// so no __syncthreads inside the step. Cell state creg[4] per thread:
// batch = mh*64 + wv*16 + (lane>>2), j = nt*16 + (lane&3)*4 + jj.
template<int NK1, bool COH1>
__device__ __forceinline__ void lstm_step(
    const u16* __restrict__ A1, int a1rowlen, const u16* __restrict__ ldsW1, int st1,
    const u16* __restrict__ A2, const u16* __restrict__ ldsW2,
    const float* __restrict__ biasp, u16* __restrict__ hdst,
    float* creg, float (*g)[69],
    int mh, int nt, int wv, int lane)
{
  const int lrow = lane & 15, kq = lane >> 4;
  const int arow = mh*64 + wv*16 + lrow;
  short8 a1[NK1], a2[16];
  {
    const u16* p1 = A1 + arow*a1rowlen + kq*8;
    #pragma unroll
    for (int k = 0; k < NK1; ++k)
      a1[k] = COH1 ? ldc8(p1 + k*32) : *(const short8*)(p1 + k*32);
    const u16* p2 = A2 + arow*512 + kq*8;
    #pragma unroll
    for (int k = 0; k < 16; ++k) a2[k] = ldc8(p2 + k*32);
  }
  floatx4 acc[4];
  #pragma unroll
  for (int nn = 0; nn < 4; ++nn) acc[nn] = (floatx4){0.f,0.f,0.f,0.f};
  #pragma unroll
  for (int nn = 0; nn < 4; ++nn){
    const u16* wb = ldsW1 + (nn*16 + lrow)*st1 + kq*8;
    #pragma unroll
    for (int k = 0; k < NK1; ++k)
      acc[nn] = __builtin_amdgcn_mfma_f32_16x16x32_bf16(a1[k], *(const short8*)(wb + k*32), acc[nn], 0,0,0);
  }
  #pragma unroll
  for (int nn = 0; nn < 4; ++nn){
    const u16* wb = ldsW2 + (nn*16 + lrow)*520 + kq*8;
    #pragma unroll
    for (int k = 0; k < 16; ++k)
      acc[nn] = __builtin_amdgcn_mfma_f32_16x16x32_bf16(a2[k], *(const short8*)(wb + k*32), acc[nn], 0,0,0);
  }
  // C/D layout: row(m) = kq*4 + r, col(n) = lane&15 -> g rows wv*16..+15 only
  #pragma unroll
  for (int nn = 0; nn < 4; ++nn){
    float bn = biasp[nn*16 + lrow];
    #pragma unroll
    for (int r = 0; r < 4; ++r)
      g[wv*16 + kq*4 + r][nn*16 + lrow] = acc[nn][r] + bn;
  }
  __builtin_amdgcn_wave_barrier();   // intra-wave LDS transpose; DS ops in-order per wave
  const int bl = lane >> 2, jq = lane & 3;
  const float* gr = g[wv*16 + bl];
  union { u16 h[4]; u64 q; } pk;
  #pragma unroll
  for (int jj = 0; jj < 4; ++jj){
    int cb = (jq*4 + jj)*4;
    float gi = gr[cb+0], gf = gr[cb+1], gg = gr[cb+2], go = gr[cb+3];
    float iv = 1.f/(1.f + expf(-gi));
    float fv = 1.f/(1.f + expf(-gf));
    float ov = 1.f/(1.f + expf(-go));
    float cn = fv*creg[jj] + iv*tanhf(gg);
    creg[jj] = cn;
    pk.h[jj] = f2b(ov * tanhf(cn));
  }
  stc64((u64*)(hdst + (mh*64 + wv*16 + bl)*512 + nt*16 + jq*4), pk.q);
}

// Flag protocol (single-producer, monotone, relaxed agent atomics) — R5-proven:
//  f0[mh*32+nt]: l0 wg; enc t -> t+1; dec s -> 257+s.   f1: l1 likewise.
//  fh[mh]: heads; after cls -> 1; after forecast s -> s+2.
// Waits: enc l0 t: f0>=t, f1>=t-1 | enc l1 u: f0>=u+1, f1>=u
//        dec l0 s: f0>=256+s, f1>=256+s | dec l1 s: f0>=257+s, f1>=256+s, fh>=s
//        heads cls: f1>=256 | forecast s: f1>=257+s

__global__ __launch_bounds__(256, 1) __attribute__((amdgpu_waves_per_eu(1, 1)))
void persist_k(PK p){
  const int w = blockIdx.x, tid = threadIdx.x;
  const int wv = tid >> 6, lane = tid & 63;
  __shared__ float g[64][69];
  extern __shared__ u16 dynW[];
  unsigned* F = p.F;

  auto setflag = [&](int idx, unsigned val){
    __syncthreads();   // release: drains vmcnt (h stores) on every wave
    if (tid == 0) __hip_atomic_store(F + idx, val, __ATOMIC_RELAXED, SCOPE_AGENT);
  };

  if (w < 128){
    const int role = w >> 6;            // 0 = layer0 chain, 1 = layer1 chain
    const int q = w & 63;
    const int mh = q >> 5, nt = q & 31;
    const int fidx = role*64 + mh*32 + nt;
    u16* WA = dynW;
    u16* WB = dynW + 64*520;
    float creg[4] = {0.f,0.f,0.f,0.f};

    if (role == 0){
      { // preload: Wx0 slice (stride 40) + W0hh slice (stride 520)
        const unsigned* sA = (const unsigned*)(p.Wx0 + nt*64*32);
        unsigned* dA = (unsigned*)WA;
        for (int i = tid; i < 64*16; i += 256){ int r = i>>4, c = i&15; dA[r*20+c] = sA[r*16+c]; }
        const unsigned* sB = (const unsigned*)(p.W0hh + (size_t)nt*64*512);
        unsigned* dB = (unsigned*)WB;
        for (int i = tid; i < 64*256; i += 256){ int r = i>>8, c = i&255; dB[r*260+c] = sB[r*256+c]; }
      }
      const float* biasp = p.Bs + nt*64;
      __syncthreads();
      for (int t = 0; t < 256; ++t){
        pollF(F, mh, t, t-1, 0);
        lstm_step<1,false>(p.Xb + t*4096, 32, WA, 40,
                           p.h0b + ((t+1)&1)*HB, WB,
                           biasp, p.h0b + (t&1)*HB, creg, g, mh, nt, wv, lane);
        setflag(fidx, t+1);
      }
      { // reload decoder l0 weights (cell state stays in regs)
        const unsigned* sA = (const unsigned*)(p.Wd0ih + (size_t)nt*64*512);
        const unsigned* sB = (const unsigned*)(p.Wd0hh + (size_t)nt*64*512);
        unsigned* dA = (unsigned*)WA; unsigned* dB = (unsigned*)WB;
        for (int i = tid; i < 64*256; i += 256){
          int r = i>>8, c = i&255;
          dA[r*260+c] = sA[r*256+c]; dB[r*260+c] = sB[r*256+c];
        }
      }
      biasp = p.Bs + 4096 + nt*64;
      __syncthreads();
      for (int s = 0; s < 12; ++s){
        int ps = (s&1)^1;
        pollF(F, mh, 256+s, 256+s, 0);
        lstm_step<16,true>(p.h1b + ps*HB, 512, WA, 520,
                           p.h0b + ps*HB, WB,
                           biasp, p.h0b + (1-ps)*HB, creg, g, mh, nt, wv, lane);
        setflag(fidx, 257+s);
      }
    } else {
      { // preload: W1ih + W1hh slices
        const unsigned* sA = (const unsigned*)(p.W1ih + (size_t)nt*64*512);
        const unsigned* sB = (const unsigned*)(p.W1hh + (size_t)nt*64*512);
        unsigned* dA = (unsigned*)WA; unsigned* dB = (unsigned*)WB;
        for (int i = tid; i < 64*256; i += 256){
          int r = i>>8, c = i&255;
          dA[r*260+c] = sA[r*256+c]; dB[r*260+c] = sB[r*256+c];
        }
      }
      const float* biasp = p.Bs + 2048 + nt*64;
      __syncthreads();
      for (int u = 0; u < 256; ++u){
        pollF(F, mh, u+1, u, 0);
        lstm_step<16,true>(p.h0b + (u&1)*HB, 512, WA, 520,
                           p.h1b + ((u+1)&1)*HB, WB,
                           biasp, p.h1b + (u&1)*HB, creg, g, mh, nt, wv, lane);
        setflag(fidx, u+1);
      }
      { // reload decoder l1 weights
        const unsigned* sA = (const unsigned*)(p.Wd1ih + (size_t)nt*64*512);
        const unsigned* sB = (const unsigned*)(p.Wd1hh + (size_t)nt*64*512);
        unsigned* dA = (unsigned*)WA; unsigned* dB = (unsigned*)WB;
        for (int i = tid; i < 64*256; i += 256){
          int r = i>>8, c = i&255;
          dA[r*260+c] = sA[r*256+c]; dB[r*260+c] = sB[r*256+c];
        }
      }
      biasp = p.Bs + 6144 + nt*64;
      __syncthreads();
      for (int s = 0; s < 12; ++s){
        int ps = (s&1)^1;
        pollF(F, mh, 257+s, 256+s, s);
        lstm_step<16,true>(p.h0b + (1-ps)*HB, 512, WA, 520,
                           p.h1b + ps*HB, WB,
                           biasp, p.h1b + (1-ps)*HB, creg, g, mh, nt, wv, lane);
        setflag(fidx, 257+s);
      }
    }
  } else if (w < 130){
    // ---- heads wg (one per mh half) ----
    const int mh = w & 1;
    const int b = tid & 63, part = tid >> 6;
    const int gb = mh*64 + b;
    { // cls + reg from h1[255] (slot 1)
      pollF(F, mh, 0, 256, 0);
      const u64* hp = (const u64*)(p.h1b + HB + gb*512 + part*128);
      float a[5] = {0.f,0.f,0.f,0.f,0.f};
      for (int c = 0; c < 32; ++c){
        u64 v = ldc64(hp + c);
        #pragma unroll
        for (int e = 0; e < 4; ++e){
          float hv = b2f((u16)(v >> (16*e)));
          int k = part*128 + c*4 + e;
          a[0] += hv * p.clsW[k];
          a[1] += hv * p.clsW[512 + k];
          a[2] += hv * p.clsW[1024 + k];
          a[3] += hv * p.clsW[1536 + k];
          a[4] += hv * p.regW[k];
        }
      }
      #pragma unroll
      for (int d = 0; d < 5; ++d) g[b][part*8 + d] = a[d];
      __syncthreads();
      if (tid < 64){
        #pragma unroll
        for (int d = 0; d < 5; ++d){
          float v = g[tid][d] + g[tid][8+d] + g[tid][16+d] + g[tid][24+d];
          if (d < 4) p.out[9216 + (mh*64 + tid)*4 + d] = v + p.clsb[d];
          else       p.out[9728 + mh*64 + tid]         = v + p.regb[0];
        }
      }
      __syncthreads();
      if (tid == 0) __hip_atomic_store(F + 128 + mh, 1u, __ATOMIC_RELAXED, SCOPE_AGENT);
    }
    for (int s = 0; s < 12; ++s){
      pollF(F, mh, 0, 257 + s, 0);
      const u64* hp = (const u64*)(p.h1b + (s&1)*HB + gb*512 + part*128);
      float a[6] = {0.f,0.f,0.f,0.f,0.f,0.f};
      for (int c = 0; c < 32; ++c){
        u64 v = ldc64(hp + c);
        #pragma unroll
        for (int e = 0; e < 4; ++e){
          float hv = b2f((u16)(v >> (16*e)));
          int k = part*128 + c*4 + e;
          #pragma unroll
          for (int d = 0; d < 6; ++d) a[d] += hv * p.fcW[d*512 + k];
        }
      }
      #pragma unroll
      for (int d = 0; d < 6; ++d) g[b][part*8 + d] = a[d];
      __syncthreads();
      if (tid < 64){
        #pragma unroll
        for (int d = 0; d < 6; ++d){
          float v = g[tid][d] + g[tid][8+d] + g[tid][16+d] + g[tid][24+d];
          p.out[(mh*64 + tid)*72 + s*6 + d] = v + p.fcb[d];
        }
      }
      __syncthreads();
      if (tid == 0)
        __hip_atomic_store(F + 128 + mh, (unsigned)(s+2), __ATOMIC_RELAXED, SCOPE_AGENT);
    }
  }
}

// ---------------- launcher ----------------

extern "C" void kernel_launch(void* const* d_in, const int* in_sizes, int n_in,
                              void* d_out, int out_size, void* d_ws, size_t ws_size,
                              hipStream_t stream){
  const float* x     = (const float*)d_in[0];
  const float* eWih0 = (const float*)d_in[1];
  const float* eWhh0 = (const float*)d_in[2];
  const float* ebih0 = (const float*)d_in[3];
  const float* ebhh0 = (const float*)d_in[4];
  const float* eWih1 = (const float*)d_in[5];
  const float* eWhh1 = (const float*)d_in[6];
  const float* ebih1 = (const float*)d_in[7];
  const float* ebhh1 = (const float*)d_in[8];
  const float* dWih0 = (const float*)d_in[9];
  const float* dWhh0 = (const float*)d_in[10];
  const float* dbih0 = (const float*)d_in[11];
  const float* dbhh0 = (const float*)d_in[12];
  const float* dWih1 = (const float*)d_in[13];
  const float* dWhh1 = (const float*)d_in[14];
  const float* dbih1 = (const float*)d_in[15];
  const float* dbhh1 = (const float*)d_in[16];
  const float* fcW   = (const float*)d_in[17];
  const float* fcb   = (const float*)d_in[18];
  const float* clsW  = (const float*)d_in[19];
  const float* clsb  = (const float*)d_in[20];
  const float* regW  = (const float*)d_in[21];
  const float* regb  = (const float*)d_in[22];
  float* out = (float*)d_out;

  uintptr_t base = (uintptr_t)d_ws;
  auto carve = [&](size_t n)->void*{
    void* p = (void*)base; base += (n + 255) & ~(size_t)255; return p;
  };
  u16* Wx0b  = (u16*)carve(2048*32*2);
  u16* We0hh = (u16*)carve(2048*512*2);
  u16* We1ih = (u16*)carve(2048*512*2);
  u16* We1hh = (u16*)carve(2048*512*2);
  u16* Wd0ih = (u16*)carve(2048*512*2);
  u16* Wd0hh = (u16*)carve(2048*512*2);
  u16* Wd1ih = (u16*)carve(2048*512*2);
  u16* Wd1hh = (u16*)carve(2048*512*2);
  float* Bs  = (float*)carve(4*2048*4);
  u16* Xb    = (u16*)carve(256*128*32*2);
  u16* h0b   = (u16*)carve(2*128*512*2);      // ping-pong bf16 h, layer0
  u16* h1b   = (u16*)carve(2*128*512*2);      // layer1
  unsigned* F = (unsigned*)carve(192*4);

  // zero h-buffers + flags (contiguous 256-aligned carves)
  (void)hipMemsetAsync(h0b, 0, 2*128*512*2 + 2*128*512*2 + 768, stream);

  reorder_w_k<<<4096,256,0,stream>>>(eWhh0, We0hh);
  reorder_w_k<<<4096,256,0,stream>>>(eWih1, We1ih);
  reorder_w_k<<<4096,256,0,stream>>>(eWhh1, We1hh);
  reorder_w_k<<<4096,256,0,stream>>>(dWih0, Wd0ih);
  reorder_w_k<<<4096,256,0,stream>>>(dWhh0, Wd0hh);
  reorder_w_k<<<4096,256,0,stream>>>(dWih1, Wd1ih);
  reorder_w_k<<<4096,256,0,stream>>>(dWhh1, Wd1hh);
  prep_wx0_k<<<256,256,0,stream>>>(eWih0, Wx0b);
  prep_bias_k<<<8,256,0,stream>>>(ebih0, ebhh0, Bs);
  prep_bias_k<<<8,256,0,stream>>>(ebih1, ebhh1, Bs + 2048);
  prep_bias_k<<<8,256,0,stream>>>(dbih0, dbhh0, Bs + 4096);
  prep_bias_k<<<8,256,0,stream>>>(dbih1, dbhh1, Bs + 6144);
  prep_x_k<<<4096,256,0,stream>>>(x, Xb);

  PK p;
  p.Xb = Xb; p.Wx0 = Wx0b; p.W0hh = We0hh; p.W1ih = We1ih; p.W1hh = We1hh;
  p.Wd0ih = Wd0ih; p.Wd0hh = Wd0hh; p.Wd1ih = Wd1ih; p.Wd1hh = Wd1hh;
  p.Bs = Bs; p.h0b = h0b; p.h1b = h1b; p.F = F;
  p.fcW = fcW; p.fcb = fcb; p.clsW = clsW; p.clsb = clsb;
  p.regW = regW; p.regb = regb; p.out = out;

  const int dynLds = 2*64*520*2;   // 133,120 B (two 64x520 u16 weight slices)
  (void)hipFuncSetAttribute((const void*)persist_k,
                            hipFuncAttributeMaxDynamicSharedMemorySize, dynLds);

  void* args[] = { &p };
  (void)hipLaunchCooperativeKernel((const void*)persist_k, dim3(130), dim3(256),
                                   args, dynLds, stream);
  (void)in_sizes; (void)n_in; (void)out_size; (void)ws_size;
}